// Round 8
// baseline (303.778 us; speedup 1.0000x reference)
//
#include <hip/hip_runtime.h>
#include <hip/hip_bf16.h>
#include <stdint.h>

#define NB 4
#define NS 4096
#define ND 128
#define KVBLK 32
#define NT32 (NS / KVBLK)        // 128 kv tiles of 32 rows
#define QBLK 128                 // 4 waves x 32 q-rows

typedef __attribute__((ext_vector_type(8))) short short8;
typedef __attribute__((ext_vector_type(4))) float f32x4;
typedef __attribute__((ext_vector_type(16))) float f32x16;
typedef __attribute__((ext_vector_type(2))) int i32x2;
typedef _Float16 f16;

// log2(e) / sqrt(128): folded into Q so scores come out in exp2 domain.
#define QSCALE 0.12751744f

__device__ __forceinline__ unsigned short f2bfu(float f) {
  __hip_bfloat16 h = __float2bfloat16(f);   // RNE; pairs fuse to v_cvt_pk_bf16_f32
  union { __hip_bfloat16 h; unsigned short u; } c; c.h = h; return c.u;
}
__device__ __forceinline__ uint32_t pack2bf(float lo, float hi) {
  return (uint32_t)f2bfu(lo) | ((uint32_t)f2bfu(hi) << 16);
}

__device__ __forceinline__ void gl_lds16(const void* g, void* l) {
  __builtin_amdgcn_global_load_lds(
      (const __attribute__((address_space(1))) uint32_t*)g,
      (__attribute__((address_space(3))) uint32_t*)l, 16, 0, 0);
}

#define MFMA16(a, b, c) __builtin_amdgcn_mfma_f32_16x16x32_bf16((a), (b), (c), 0, 0, 0)
#define MFMA32(a, b, c) __builtin_amdgcn_mfma_f32_32x32x16_bf16((a), (b), (c), 0, 0, 0)

#if __has_builtin(__builtin_amdgcn_permlane32_swap)
#define PLSWAP(lo_, hi_)                                                        \
  { i32x2 r_ = __builtin_amdgcn_permlane32_swap((int)(lo_), (int)(hi_), false,  \
                                                false);                         \
    lo_ = (uint32_t)r_[0]; hi_ = (uint32_t)r_[1]; }
#else
#define PLSWAP(lo_, hi_)                                                        \
  { uint32_t sA_ = hi ? (lo_) : (hi_);                                          \
    uint32_t rA_ = (uint32_t)__shfl_xor((int)sA_, 32, 64);                      \
    uint32_t nl_ = hi ? rA_ : (lo_);                                            \
    uint32_t nh_ = hi ? (hi_) : rA_;                                            \
    lo_ = nl_; hi_ = nh_; }
#endif

// ---------------------------------------------------------------------------
// Preconvert x and W to bf16 (linear row-major) so proj can gl_lds-stage.
// ---------------------------------------------------------------------------
__global__ __launch_bounds__(512) void preconv_kernel(
    const float* __restrict__ x,
    const float* __restrict__ Wq, const float* __restrict__ Wk,
    const float* __restrict__ Wv,
    unsigned short* __restrict__ xb, unsigned short* __restrict__ Wb)
{
  const size_t xg8 = (size_t)NB * NS * ND / 8;   // 262144
  size_t i = (size_t)blockIdx.x * 512 + threadIdx.x;
  const float* src; unsigned short* dst; size_t off;
  if (i < xg8) { src = x; dst = xb; off = i * 8; }
  else {
    size_t j = i - xg8;                          // < 6144
    int which = (int)(j / 2048);
    src = which == 0 ? Wq : which == 1 ? Wk : Wv;
    dst = Wb;
    off = j * 8;
    src = src - (size_t)which * 16384;
  }
  float4 a = *(const float4*)(src + off), b2 = *(const float4*)(src + off + 4);
  short8 o;
  o[0] = (short)f2bfu(a.x);  o[1] = (short)f2bfu(a.y);
  o[2] = (short)f2bfu(a.z);  o[3] = (short)f2bfu(a.w);
  o[4] = (short)f2bfu(b2.x); o[5] = (short)f2bfu(b2.y);
  o[6] = (short)f2bfu(b2.z); o[7] = (short)f2bfu(b2.w);
  *(short8*)(dst + off) = o;
}

// ---------------------------------------------------------------------------
// Projection (bf16 in): T = x @ W^T + b  (blockIdx.z: 0=Q,1=K,2=V)
// ---------------------------------------------------------------------------
__global__ __launch_bounds__(256) void proj_kernel(
    const unsigned short* __restrict__ xb, const unsigned short* __restrict__ Wb,
    const float* __restrict__ bq, const float* __restrict__ bk,
    const float* __restrict__ bv,
    unsigned short* __restrict__ Qo, unsigned short* __restrict__ Ko,
    unsigned short* __restrict__ Vt)
{
  __shared__ unsigned short Xs[64 * 128];    // 16 KB
  __shared__ unsigned short Ws[128 * 128];   // 32 KB (overlaid as Tt for V)

  const int tile = blockIdx.x, b = blockIdx.y, which = blockIdx.z;
  const float* bias = which == 0 ? bq : which == 1 ? bk : bv;
  const int t = threadIdx.x, wave = t >> 6, lane = t & 63;
  const int lr = lane & 15, lg = lane >> 4;

  const char* xsrc = (const char*)(xb + ((size_t)b * NS + (size_t)tile * 64) * ND);
#pragma unroll
  for (int i = wave; i < 16; i += 4) {
    int y = i * 1024 + lane * 16;
    int so = y ^ (((y >> 8) & 7) << 4);
    gl_lds16(xsrc + so, (char*)Xs + y);
  }
  const char* wsrc = (const char*)(Wb + (size_t)which * 16384);
#pragma unroll
  for (int i = wave; i < 32; i += 4) {
    int y = i * 1024 + lane * 16;
    int so = y ^ (((y >> 8) & 7) << 4);
    gl_lds16(wsrc + so, (char*)Ws + y);
  }
  __syncthreads();

  short8 af[4];
#pragma unroll
  for (int kk = 0; kk < 4; ++kk) {
    int row = wave * 16 + lr;
    int ba = (row * 256 + kk * 64 + lg * 16) ^ ((row & 7) << 4);
    af[kk] = *(const short8*)((const char*)Xs + ba);
  }
  f32x4 acc[8] = {};
#pragma unroll
  for (int kk = 0; kk < 4; ++kk) {
#pragma unroll
    for (int nf = 0; nf < 8; ++nf) {
      int n = nf * 16 + lr;
      int ba = (n * 256 + kk * 64 + lg * 16) ^ ((n & 7) << 4);
      short8 bf = *(const short8*)((const char*)Ws + ba);
      acc[nf] = MFMA16(af[kk], bf, acc[nf]);
    }
  }

  if (which < 2) {
    unsigned short* Out = (which == 0) ? Qo : Ko;
    const float sc = (which == 0) ? QSCALE : 1.0f;
#pragma unroll
    for (int nf = 0; nf < 8; ++nf) {
      float bb = bias[nf * 16 + lr];
#pragma unroll
      for (int r = 0; r < 4; ++r) {
        float v = (acc[nf][r] + bb) * sc;
        int row = tile * 64 + wave * 16 + lg * 4 + r;
        Out[((size_t)b * NS + row) * ND + nf * 16 + lr] = f2bfu(v);
      }
    }
  } else {
    __syncthreads();                 // all MFMA reads of Ws done
    unsigned short* Tt = Ws;         // [128][72] overlay
#pragma unroll
    for (int nf = 0; nf < 8; ++nf) {
      float bb = bias[nf * 16 + lr];
#pragma unroll
      for (int r = 0; r < 4; ++r) {
        int e = nf * 16 + lr;
        int sl = wave * 16 + lg * 4 + r;
        Tt[e * 72 + sl] = f2bfu(acc[nf][r] + bb);
      }
    }
    __syncthreads();
    int e = t >> 1, off = (t & 1) * 32;
    const short8* src = (const short8*)(Tt + e * 72 + off);
    short8* dst = (short8*)(Vt + ((size_t)b * ND + e) * NS + (size_t)tile * 64 + off);
#pragma unroll
    for (int i = 0; i < 4; ++i) dst[i] = src[i];
  }
}

// ---------------------------------------------------------------------------
// Flash attention + fused last-block combine. 4 waves x 32 q-rows, KVBLK=32,
// K+V full double-buffer (32 KB), one barrier/tile, T14 reg-staging.
// Grid = 32qt x NB x NC = 1024 @ NC=8 -> 4 blocks/CU. The last chunk block
// to finish a (b,qt) group reduces the partials (L2-hot) and writes Out.
// ---------------------------------------------------------------------------
template <int NC>
__global__ __launch_bounds__(256, 4) void attn_kernel(
    const unsigned short* __restrict__ Q, const unsigned short* __restrict__ K,
    const unsigned short* __restrict__ Vt, f16* __restrict__ OP,
    float* __restrict__ Mp, float* __restrict__ Lp,
    float* __restrict__ Out, int* __restrict__ cnt)
{
  __shared__ char smem[38912];   // main: K0|K1|V0|V1 (8KB ea); combine overlay

  const int Lid = blockIdx.x;
  constexpr int ngroups = NB * NC;
  int g, qt;
  if constexpr ((ngroups & 7) == 0) {
    int xcd = Lid & 7, s2 = Lid >> 3;
    qt = s2 & 31;
    g = xcd * (ngroups >> 3) + (s2 >> 5);
  } else { qt = Lid & 31; g = Lid >> 5; }
  const int b = g / NC, c = g - b * NC;   // b-major: XCD shares Q(b)

  constexpr int ntpc = NT32 / NC;
  const int tstart = c * ntpc;

  const int t = threadIdx.x, wave = t >> 6, lane = t & 63;
  const int lq = lane & 31, hi = lane >> 5;

  const int qrow = qt * QBLK + wave * 32 + lq;
  short8 qf[8];
  const unsigned short* Qb = Q + ((size_t)b * NS + qrow) * ND;
#pragma unroll
  for (int kt = 0; kt < 8; ++kt) qf[kt] = *(const short8*)(Qb + kt * 16 + hi * 8);

  const char* Kbase = (const char*)(K + (size_t)b * NS * ND) +
                      (size_t)tstart * (KVBLK * ND * 2);
  const char* Vbase = (const char*)(Vt + (size_t)b * ND * NS) +
                      (size_t)tstart * (KVBLK * 2);

  // T14 staging: per wave 2x1KB of K and 2x1KB of V (global->reg)
  short8 rk[2], rv[2];
  auto ldKV = [&](int tt) {
    const char* ksrc = Kbase + (size_t)tt * 8192;
    const char* vsrc = Vbase + (size_t)tt * 64;
#pragma unroll
    for (int j = 0; j < 2; ++j) {
      int y = (wave * 2 + j) * 1024 + lane * 16;
      int so = y ^ (((y >> 8) & 7) << 4);            // K row = 256B
      rk[j] = *(const short8*)(ksrc + so);
      int d = y >> 6, col = y & 63;                  // V row = 64B
      int cx = col ^ (((d >> 1) & 3) << 4);
      rv[j] = *(const short8*)(vsrc + (size_t)d * (NS * 2) + cx);
    }
  };
  auto wrKV = [&](int p) {
    char* kd = smem + p * 8192;
    char* vd = smem + 16384 + p * 8192;
#pragma unroll
    for (int j = 0; j < 2; ++j) {
      int y = (wave * 2 + j) * 1024 + lane * 16;
      *(short8*)(kd + y) = rk[j];
      *(short8*)(vd + y) = rv[j];
    }
  };

  f32x16 oacc[4] = {};
  float m = -1e30f, l = 0.f;

  ldKV(0);
  wrKV(0);
  __syncthreads();

  for (int tt = 0; tt < ntpc; ++tt) {
    const int p = tt & 1;
    const char* kb = smem + p * 8192;
    const char* vb = smem + 16384 + p * 8192;
    const bool more = (tt + 1 < ntpc);
    if (more) ldKV(tt + 1);          // issue early; vmcnt waited at wrKV

    // ---- QK^T (swapped): D[kv32][q32] ----
    f32x16 s0 = {};
    __builtin_amdgcn_s_setprio(1);
#pragma unroll
    for (int kt = 0; kt < 8; ++kt) {
      int co = (kt * 32 + hi * 16) ^ ((lq & 7) << 4);
      short8 k0 = *(const short8*)(kb + lq * 256 + co);
      s0 = MFMA32(k0, qf[kt], s0);
    }
    __builtin_amdgcn_s_setprio(0);

    // ---- lane-local online softmax with defer-max (THR=8) ----
    float x0 = fmaxf(s0[0], s0[1]), x1 = fmaxf(s0[2], s0[3]);
    float x2 = fmaxf(s0[4], s0[5]), x3 = fmaxf(s0[6], s0[7]);
#pragma unroll
    for (int r = 8; r < 16; r += 4) {
      x0 = fmaxf(x0, s0[r]);     x1 = fmaxf(x1, s0[r + 1]);
      x2 = fmaxf(x2, s0[r + 2]); x3 = fmaxf(x3, s0[r + 3]);
    }
    float px = fmaxf(fmaxf(x0, x1), fmaxf(x2, x3));
    px = fmaxf(px, __shfl_xor(px, 32, 64));      // sync m across lane pair
    if (__any(px > m + 8.f)) {
      float mn = fmaxf(m, px);
      float corr = exp2f(m - mn);
      m = mn;
      l *= corr;
#pragma unroll
      for (int dt = 0; dt < 4; ++dt)
#pragma unroll
        for (int r = 0; r < 16; ++r) oacc[dt][r] *= corr;
    }

    float p0[16];
    float u0 = 0.f, u1 = 0.f, u2 = 0.f, u3 = 0.f;
#pragma unroll
    for (int r = 0; r < 16; r += 4) {
      p0[r]     = exp2f(s0[r] - m);
      p0[r + 1] = exp2f(s0[r + 1] - m);
      p0[r + 2] = exp2f(s0[r + 2] - m);
      p0[r + 3] = exp2f(s0[r + 3] - m);
      u0 += p0[r]; u1 += p0[r + 1]; u2 += p0[r + 2]; u3 += p0[r + 3];
    }
    l += (u0 + u1) + (u2 + u3);   // lane-half partial; paired in epilogue

    // ---- pack P -> bf16 pairs; permlane half-exchange; PV B-frags ----
    uint32_t pk[8];
#pragma unroll
    for (int i = 0; i < 8; ++i) pk[i] = pack2bf(p0[2 * i], p0[2 * i + 1]);
    short8 pfrag[2];
#pragma unroll
    for (int kt2 = 0; kt2 < 2; ++kt2) {
      uint32_t e0 = pk[4 * kt2 + 0], e1 = pk[4 * kt2 + 1];
      uint32_t e2 = pk[4 * kt2 + 2], e3 = pk[4 * kt2 + 3];
      PLSWAP(e0, e2);
      PLSWAP(e1, e3);
      union { uint32_t u[4]; short8 s; } pf;
      pf.u[0] = e0; pf.u[1] = e1; pf.u[2] = e2; pf.u[3] = e3;
      pfrag[kt2] = pf.s;
    }

    if (more) wrKV(p ^ 1);   // stage next tile now; overlaps PV MFMA below

    // ---- PV (swapped): oacc[dt] += V^T[dt] . P^T -> D[d][q] ----
    const int vsw = ((lq >> 1) & 3) << 4;
    __builtin_amdgcn_s_setprio(1);
#pragma unroll
    for (int dt = 0; dt < 4; ++dt) {
      int rowb = (dt * 32 + lq) * 64;
#pragma unroll
      for (int kt2 = 0; kt2 < 2; ++kt2) {
        int co = (kt2 * 32 + hi * 16) ^ vsw;
        short8 vf = *(const short8*)(vb + rowb + co);
        oacc[dt] = MFMA32(vf, pfrag[kt2], oacc[dt]);
      }
    }
    __builtin_amdgcn_s_setprio(0);

    __syncthreads();                  // one barrier per tile
  }

  // ---- epilogue: pair-sum l; fp16 unnormalized O^T partial + m,l ----
  float lt = l + __shfl_xor(l, 32, 64);
  f16* OPb = OP + ((size_t)(c * NB + b) * ND) * NS + qrow;
#pragma unroll
  for (int dt = 0; dt < 4; ++dt)
#pragma unroll
    for (int r = 0; r < 16; ++r) {
      int d = dt * 32 + (r & 3) + 8 * (r >> 2) + 4 * hi;
      OPb[(size_t)d * NS] = (f16)oacc[dt][r];
    }
  if (hi == 0) {
    Mp[(size_t)(c * NB + b) * NS + qrow] = m;
    Lp[(size_t)(c * NB + b) * NS + qrow] = lt;
  }

  // ---- fused combine: last block of the (b,qt) group reduces partials ----
  __threadfence();                 // release: OP/Mp/Lp device-visible
  __syncthreads();
  int* flagp = (int*)(smem + 38904);
  if (t == 0) {
    int old = atomicAdd(&cnt[b * 32 + qt], 1);
    *flagp = (old == NC - 1);
  }
  __syncthreads();
  if (!*flagp) return;
  __threadfence();                 // acquire: see other blocks' partials

  float* wn = (float*)smem;                 // [NC][128] <= 4 KB
  float* LTb = (float*)(smem + 4096);       // [64][129] = 33 KB
  if (t < 128) {
    size_t qg = (size_t)qt * 128 + t;
    float mv[NC], wloc[NC];
#pragma unroll
    for (int cc = 0; cc < NC; ++cc)
      mv[cc] = Mp[(size_t)(cc * NB + b) * NS + qg];
    float mx = mv[0];
#pragma unroll
    for (int cc = 1; cc < NC; ++cc) mx = fmaxf(mx, mv[cc]);
    float Lt = 0.f;
#pragma unroll
    for (int cc = 0; cc < NC; ++cc) {
      float w = exp2f(mv[cc] - mx);
      Lt += w * Lp[(size_t)(cc * NB + b) * NS + qg];
      wloc[cc] = w;
    }
    float inv = 1.0f / Lt;
#pragma unroll
    for (int cc = 0; cc < NC; ++cc) wn[cc * 128 + t] = wloc[cc] * inv;
  }
  __syncthreads();

#pragma unroll
  for (int half = 0; half < 2; ++half) {
    const int so = (t & 7) * 8;     // 8 q's per thread (16B along s)
    const int dl = t >> 3;          // 32 d's per pass
    const size_t sbase = (size_t)qt * 128 + half * 64 + so;
#pragma unroll
    for (int dblk = 0; dblk < 4; ++dblk) {
      int d = dblk * 32 + dl;
      float a0 = 0, a1 = 0, a2 = 0, a3 = 0, a4 = 0, a5 = 0, a6 = 0, a7 = 0;
#pragma unroll
      for (int cc = 0; cc < NC; ++cc) {
        const f16* src = OP + ((size_t)(cc * NB + b) * ND + d) * NS + sbase;
        short8 v = *(const short8*)src;
        const float* w = wn + cc * 128 + half * 64 + so;
        union { short s; f16 h; } u;
        u.s = v[0]; a0 += w[0] * (float)u.h;
        u.s = v[1]; a1 += w[1] * (float)u.h;
        u.s = v[2]; a2 += w[2] * (float)u.h;
        u.s = v[3]; a3 += w[3] * (float)u.h;
        u.s = v[4]; a4 += w[4] * (float)u.h;
        u.s = v[5]; a5 += w[5] * (float)u.h;
        u.s = v[6]; a6 += w[6] * (float)u.h;
        u.s = v[7]; a7 += w[7] * (float)u.h;
      }
      LTb[(so + 0) * 129 + d] = a0; LTb[(so + 1) * 129 + d] = a1;
      LTb[(so + 2) * 129 + d] = a2; LTb[(so + 3) * 129 + d] = a3;
      LTb[(so + 4) * 129 + d] = a4; LTb[(so + 5) * 129 + d] = a5;
      LTb[(so + 6) * 129 + d] = a6; LTb[(so + 7) * 129 + d] = a7;
    }
    __syncthreads();
    const int d2 = t & 127, qh = t >> 7;
    float* Ob = Out + ((size_t)b * NS + (size_t)qt * 128 + half * 64) * ND;
#pragma unroll 8
    for (int pass = 0; pass < 32; ++pass) {
      int qq = pass * 2 + qh;
      Ob[(size_t)qq * ND + d2] = LTb[qq * 129 + d2];
    }
    __syncthreads();
  }
}

extern "C" void kernel_launch(void* const* d_in, const int* in_sizes, int n_in,
                              void* d_out, int out_size, void* d_ws, size_t ws_size,
                              hipStream_t stream) {
  const float* x  = (const float*)d_in[0];
  const float* Wq = (const float*)d_in[1];
  const float* bq = (const float*)d_in[2];
  const float* Wk = (const float*)d_in[3];
  const float* bk = (const float*)d_in[4];
  const float* Wv = (const float*)d_in[5];
  const float* bv = (const float*)d_in[6];

  const size_t elems = (size_t)NB * NS * ND;
  char* base = (char*)d_ws;
  unsigned short* Qw  = (unsigned short*)base;
  unsigned short* Kw  = Qw + elems;
  unsigned short* Vtw = Kw + elems;
  char* region2 = base + 3 * elems * 2;            // 12 MB offset

  // split-KV factor: largest of {8,4,2,1} fitting ws (fp16 OP partials).
  int nchunk = 8;
  while (nchunk > 1) {
    size_t need = 3 * elems * 2 +
                  (size_t)nchunk * (elems * 2 + 2 * (size_t)NB * NS * 4) + 1024;
    if (need <= ws_size) break;
    nchunk >>= 1;
  }

  // xb16/Wb16 alias the OP region (proj finishes before attn writes OP).
  unsigned short* xb16 = (unsigned short*)region2;
  unsigned short* Wb16 = xb16 + elems;
  f16* OPw = (f16*)region2;
  float* Mpw = (float*)(region2 + (size_t)nchunk * elems * 2);
  float* Lpw = Mpw + (size_t)nchunk * NB * NS;
  int* cntw = (int*)(Lpw + (size_t)nchunk * NB * NS);

  hipMemsetAsync(cntw, 0, NB * 32 * sizeof(int), stream);

  preconv_kernel<<<dim3(524), 512, 0, stream>>>(x, Wq, Wk, Wv, xb16, Wb16);

  proj_kernel<<<dim3(NS / 64, NB, 3), 256, 0, stream>>>(
      xb16, Wb16, bq, bk, bv, Qw, Kw, Vtw);

  float* out = (float*)d_out;
  switch (nchunk) {
    case 8: attn_kernel<8><<<dim3(32 * NB * 8), 256, 0, stream>>>(
                Qw, Kw, Vtw, OPw, Mpw, Lpw, out, cntw); break;
    case 4: attn_kernel<4><<<dim3(32 * NB * 4), 256, 0, stream>>>(
                Qw, Kw, Vtw, OPw, Mpw, Lpw, out, cntw); break;
    case 2: attn_kernel<2><<<dim3(32 * NB * 2), 256, 0, stream>>>(
                Qw, Kw, Vtw, OPw, Mpw, Lpw, out, cntw); break;
    default: attn_kernel<1><<<dim3(32 * NB * 1), 256, 0, stream>>>(
                Qw, Kw, Vtw, OPw, Mpw, Lpw, out, cntw); break;
  }
}

// Round 9
// 75.077 us; speedup vs baseline: 4.0462x; 4.0462x over previous
//
#include <hip/hip_runtime.h>
#include <hip/hip_bf16.h>
#include <stdint.h>

#define NB 4
#define NS 4096
#define ND 128
#define KVBLK 32
#define NT32 (NS / KVBLK)        // 128 kv tiles of 32 rows
#define QBLK 128                 // 4 waves x 32 q-rows

typedef __attribute__((ext_vector_type(8))) short short8;
typedef __attribute__((ext_vector_type(4))) float f32x4;
typedef __attribute__((ext_vector_type(16))) float f32x16;
typedef __attribute__((ext_vector_type(2))) int i32x2;
typedef _Float16 f16;

// log2(e) / sqrt(128): folded into Q so scores come out in exp2 domain.
#define QSCALE 0.12751744f

__device__ __forceinline__ unsigned short f2bfu(float f) {
  __hip_bfloat16 h = __float2bfloat16(f);   // RNE; pairs fuse to v_cvt_pk_bf16_f32
  union { __hip_bfloat16 h; unsigned short u; } c; c.h = h; return c.u;
}
__device__ __forceinline__ uint32_t pack2bf(float lo, float hi) {
  return (uint32_t)f2bfu(lo) | ((uint32_t)f2bfu(hi) << 16);
}

__device__ __forceinline__ void gl_lds16(const void* g, void* l) {
  __builtin_amdgcn_global_load_lds(
      (const __attribute__((address_space(1))) uint32_t*)g,
      (__attribute__((address_space(3))) uint32_t*)l, 16, 0, 0);
}

#define MFMA16(a, b, c) __builtin_amdgcn_mfma_f32_16x16x32_bf16((a), (b), (c), 0, 0, 0)
#define MFMA32(a, b, c) __builtin_amdgcn_mfma_f32_32x32x16_bf16((a), (b), (c), 0, 0, 0)

#if __has_builtin(__builtin_amdgcn_permlane32_swap)
#define PLSWAP(lo_, hi_)                                                        \
  { i32x2 r_ = __builtin_amdgcn_permlane32_swap((int)(lo_), (int)(hi_), false,  \
                                                false);                         \
    lo_ = (uint32_t)r_[0]; hi_ = (uint32_t)r_[1]; }
#else
#define PLSWAP(lo_, hi_)                                                        \
  { uint32_t sA_ = hi ? (lo_) : (hi_);                                          \
    uint32_t rA_ = (uint32_t)__shfl_xor((int)sA_, 32, 64);                      \
    uint32_t nl_ = hi ? rA_ : (lo_);                                            \
    uint32_t nh_ = hi ? (hi_) : rA_;                                            \
    lo_ = nl_; hi_ = nh_; }
#endif

// ---------------------------------------------------------------------------
// Preconvert x and W to bf16 (linear row-major) so proj can gl_lds-stage.
// ---------------------------------------------------------------------------
__global__ __launch_bounds__(512) void preconv_kernel(
    const float* __restrict__ x,
    const float* __restrict__ Wq, const float* __restrict__ Wk,
    const float* __restrict__ Wv,
    unsigned short* __restrict__ xb, unsigned short* __restrict__ Wb)
{
  const size_t xg8 = (size_t)NB * NS * ND / 8;   // 262144
  size_t i = (size_t)blockIdx.x * 512 + threadIdx.x;
  const float* src; unsigned short* dst; size_t off;
  if (i < xg8) { src = x; dst = xb; off = i * 8; }
  else {
    size_t j = i - xg8;                          // < 6144
    int which = (int)(j / 2048);
    src = which == 0 ? Wq : which == 1 ? Wk : Wv;
    dst = Wb;
    off = j * 8;
    src = src - (size_t)which * 16384;
  }
  float4 a = *(const float4*)(src + off), b2 = *(const float4*)(src + off + 4);
  short8 o;
  o[0] = (short)f2bfu(a.x);  o[1] = (short)f2bfu(a.y);
  o[2] = (short)f2bfu(a.z);  o[3] = (short)f2bfu(a.w);
  o[4] = (short)f2bfu(b2.x); o[5] = (short)f2bfu(b2.y);
  o[6] = (short)f2bfu(b2.z); o[7] = (short)f2bfu(b2.w);
  *(short8*)(dst + off) = o;
}

// ---------------------------------------------------------------------------
// Projection (bf16 in): T = x @ W^T + b  (blockIdx.z: 0=Q,1=K,2=V)
// ---------------------------------------------------------------------------
__global__ __launch_bounds__(256) void proj_kernel(
    const unsigned short* __restrict__ xb, const unsigned short* __restrict__ Wb,
    const float* __restrict__ bq, const float* __restrict__ bk,
    const float* __restrict__ bv,
    unsigned short* __restrict__ Qo, unsigned short* __restrict__ Ko,
    unsigned short* __restrict__ Vt)
{
  __shared__ unsigned short Xs[64 * 128];    // 16 KB
  __shared__ unsigned short Ws[128 * 128];   // 32 KB (overlaid as Tt for V)

  const int tile = blockIdx.x, b = blockIdx.y, which = blockIdx.z;
  const float* bias = which == 0 ? bq : which == 1 ? bk : bv;
  const int t = threadIdx.x, wave = t >> 6, lane = t & 63;
  const int lr = lane & 15, lg = lane >> 4;

  const char* xsrc = (const char*)(xb + ((size_t)b * NS + (size_t)tile * 64) * ND);
#pragma unroll
  for (int i = wave; i < 16; i += 4) {
    int y = i * 1024 + lane * 16;
    int so = y ^ (((y >> 8) & 7) << 4);
    gl_lds16(xsrc + so, (char*)Xs + y);
  }
  const char* wsrc = (const char*)(Wb + (size_t)which * 16384);
#pragma unroll
  for (int i = wave; i < 32; i += 4) {
    int y = i * 1024 + lane * 16;
    int so = y ^ (((y >> 8) & 7) << 4);
    gl_lds16(wsrc + so, (char*)Ws + y);
  }
  __syncthreads();

  short8 af[4];
#pragma unroll
  for (int kk = 0; kk < 4; ++kk) {
    int row = wave * 16 + lr;
    int ba = (row * 256 + kk * 64 + lg * 16) ^ ((row & 7) << 4);
    af[kk] = *(const short8*)((const char*)Xs + ba);
  }
  f32x4 acc[8] = {};
#pragma unroll
  for (int kk = 0; kk < 4; ++kk) {
#pragma unroll
    for (int nf = 0; nf < 8; ++nf) {
      int n = nf * 16 + lr;
      int ba = (n * 256 + kk * 64 + lg * 16) ^ ((n & 7) << 4);
      short8 bf = *(const short8*)((const char*)Ws + ba);
      acc[nf] = MFMA16(af[kk], bf, acc[nf]);
    }
  }

  if (which < 2) {
    unsigned short* Out = (which == 0) ? Qo : Ko;
    const float sc = (which == 0) ? QSCALE : 1.0f;
#pragma unroll
    for (int nf = 0; nf < 8; ++nf) {
      float bb = bias[nf * 16 + lr];
#pragma unroll
      for (int r = 0; r < 4; ++r) {
        float v = (acc[nf][r] + bb) * sc;
        int row = tile * 64 + wave * 16 + lg * 4 + r;
        Out[((size_t)b * NS + row) * ND + nf * 16 + lr] = f2bfu(v);
      }
    }
  } else {
    __syncthreads();                 // all MFMA reads of Ws done
    unsigned short* Tt = Ws;         // [128][72] overlay
#pragma unroll
    for (int nf = 0; nf < 8; ++nf) {
      float bb = bias[nf * 16 + lr];
#pragma unroll
      for (int r = 0; r < 4; ++r) {
        int e = nf * 16 + lr;
        int sl = wave * 16 + lg * 4 + r;
        Tt[e * 72 + sl] = f2bfu(acc[nf][r] + bb);
      }
    }
    __syncthreads();
    int e = t >> 1, off = (t & 1) * 32;
    const short8* src = (const short8*)(Tt + e * 72 + off);
    short8* dst = (short8*)(Vt + ((size_t)b * ND + e) * NS + (size_t)tile * 64 + off);
#pragma unroll
    for (int i = 0; i < 4; ++i) dst[i] = src[i];
  }
}

// ---------------------------------------------------------------------------
// Flash attention: 4 waves x 32 q-rows, KVBLK=32, K+V full double-buffer
// (32 KB LDS -> 3 blocks/CU), ONE barrier per tile, gl_lds staging (no reg
// round-trip; vmcnt drained at the barrier after a full tile of compute).
// K swizzle (row&15)<<4 -> 2-way bank aliasing (free). fp16 OP partials.
// NOTE: combined VGPR+AGPR budget: oacc=64 AGPR + ~75 arch must stay <=170
// (3 blocks/CU). Do NOT force 4 blocks/CU -- it spills (round 8: 5x slower).
// ---------------------------------------------------------------------------
__global__ __launch_bounds__(256, 3) void attn_kernel(
    const unsigned short* __restrict__ Q, const unsigned short* __restrict__ K,
    const unsigned short* __restrict__ Vt, f16* __restrict__ OP,
    float* __restrict__ Mp, float* __restrict__ Lp, int nchunk)
{
  __shared__ char smem[32768];   // K0|K1|V0|V1, 8 KB each

  const int Lid = blockIdx.x;
  const int ngroups = NB * nchunk;
  int g, qt;
  if ((ngroups & 7) == 0) {
    int xcd = Lid & 7, s2 = Lid >> 3;
    qt = s2 & 31;
    g = xcd * (ngroups >> 3) + (s2 >> 5);
  } else { qt = Lid & 31; g = Lid >> 5; }
  const int b = g / nchunk, c = g - b * nchunk;   // b-major: XCD shares Q(b)

  // ragged chunk split of 128 kv tiles
  const int cbase = NT32 / nchunk, crem = NT32 - cbase * nchunk;
  const int tstart = c * cbase + (c < crem ? c : crem);
  const int ntpc = cbase + (c < crem ? 1 : 0);

  const int t = threadIdx.x, wave = t >> 6, lane = t & 63;
  const int lq = lane & 31, hi = lane >> 5;

  const int qrow = qt * QBLK + wave * 32 + lq;
  short8 qf[8];
  const unsigned short* Qb = Q + ((size_t)b * NS + qrow) * ND;
#pragma unroll
  for (int kt = 0; kt < 8; ++kt) qf[kt] = *(const short8*)(Qb + kt * 16 + hi * 8);

  const char* Kbase = (const char*)(K + (size_t)b * NS * ND) +
                      (size_t)tstart * (KVBLK * ND * 2);
  const char* Vbase = (const char*)(Vt + (size_t)b * ND * NS) +
                      (size_t)tstart * (KVBLK * 2);

  // gl_lds staging: per wave 2 KB of K and 2 KB of V (2 issues each)
  auto stage = [&](int p, int tt) {
    const char* ksrc = Kbase + (size_t)tt * 8192;
    const char* vsrc = Vbase + (size_t)tt * 64;
    char* kd = smem + p * 8192;
    char* vd = smem + 16384 + p * 8192;
#pragma unroll
    for (int j = 0; j < 2; ++j) {
      int y = (wave * 2 + j) * 1024 + lane * 16;
      int so = y ^ (((y >> 8) & 15) << 4);           // K row = 256B, 16-slot swz
      gl_lds16(ksrc + so, kd + y);
      int d = y >> 6, col = y & 63;                  // V row = 64B
      int cx = col ^ (((d >> 1) & 3) << 4);
      gl_lds16(vsrc + (size_t)d * (NS * 2) + cx, vd + y);
    }
  };

  f32x16 oacc[4] = {};
  float m = -1e30f, l = 0.f;

  stage(0, 0);
  __syncthreads();

  for (int tt = 0; tt < ntpc; ++tt) {
    const int p = tt & 1;
    const char* kb = smem + p * 8192;
    const char* vb = smem + 16384 + p * 8192;
    if (tt + 1 < ntpc) stage(p ^ 1, tt + 1);   // in-flight across the tile

    // ---- QK^T (swapped): D[kv32][q32] ----
    f32x16 s0 = {};
    const int ksw = (lq & 15) << 4;
    __builtin_amdgcn_s_setprio(1);
#pragma unroll
    for (int kt = 0; kt < 8; ++kt) {
      int co = (kt * 32 + hi * 16) ^ ksw;
      short8 k0 = *(const short8*)(kb + lq * 256 + co);
      s0 = MFMA32(k0, qf[kt], s0);
    }
    __builtin_amdgcn_s_setprio(0);

    // ---- lane-local online softmax with defer-max (THR=8) ----
    float x0 = fmaxf(s0[0], s0[1]), x1 = fmaxf(s0[2], s0[3]);
    float x2 = fmaxf(s0[4], s0[5]), x3 = fmaxf(s0[6], s0[7]);
#pragma unroll
    for (int r = 8; r < 16; r += 4) {
      x0 = fmaxf(x0, s0[r]);     x1 = fmaxf(x1, s0[r + 1]);
      x2 = fmaxf(x2, s0[r + 2]); x3 = fmaxf(x3, s0[r + 3]);
    }
    float px = fmaxf(fmaxf(x0, x1), fmaxf(x2, x3));
    px = fmaxf(px, __shfl_xor(px, 32, 64));      // sync m across lane pair
    if (__any(px > m + 8.f)) {
      float mn = fmaxf(m, px);
      float corr = exp2f(m - mn);
      m = mn;
      l *= corr;
#pragma unroll
      for (int dt = 0; dt < 4; ++dt)
#pragma unroll
        for (int r = 0; r < 16; ++r) oacc[dt][r] *= corr;
    }

    // exp2 in place (s0 becomes P), accumulate l
    float u0 = 0.f, u1 = 0.f, u2 = 0.f, u3 = 0.f;
#pragma unroll
    for (int r = 0; r < 16; r += 4) {
      s0[r]     = exp2f(s0[r] - m);
      s0[r + 1] = exp2f(s0[r + 1] - m);
      s0[r + 2] = exp2f(s0[r + 2] - m);
      s0[r + 3] = exp2f(s0[r + 3] - m);
      u0 += s0[r]; u1 += s0[r + 1]; u2 += s0[r + 2]; u3 += s0[r + 3];
    }
    l += (u0 + u1) + (u2 + u3);   // lane-half partial; paired in epilogue

    // ---- pack P -> bf16 pairs; permlane half-exchange; PV B-frags ----
    uint32_t pk[8];
#pragma unroll
    for (int i = 0; i < 8; ++i) pk[i] = pack2bf(s0[2 * i], s0[2 * i + 1]);
    short8 pfrag[2];
#pragma unroll
    for (int kt2 = 0; kt2 < 2; ++kt2) {
      uint32_t e0 = pk[4 * kt2 + 0], e1 = pk[4 * kt2 + 1];
      uint32_t e2 = pk[4 * kt2 + 2], e3 = pk[4 * kt2 + 3];
      PLSWAP(e0, e2);
      PLSWAP(e1, e3);
      union { uint32_t u[4]; short8 s; } pf;
      pf.u[0] = e0; pf.u[1] = e1; pf.u[2] = e2; pf.u[3] = e3;
      pfrag[kt2] = pf.s;
    }

    // ---- PV (swapped): oacc[dt] += V^T[dt] . P^T -> D[d][q] ----
    const int vsw = ((lq >> 1) & 3) << 4;
    __builtin_amdgcn_s_setprio(1);
#pragma unroll
    for (int dt = 0; dt < 4; ++dt) {
      int rowb = (dt * 32 + lq) * 64;
#pragma unroll
      for (int kt2 = 0; kt2 < 2; ++kt2) {
        int co = (kt2 * 32 + hi * 16) ^ vsw;
        short8 vf = *(const short8*)(vb + rowb + co);
        oacc[dt] = MFMA32(vf, pfrag[kt2], oacc[dt]);
      }
    }
    __builtin_amdgcn_s_setprio(0);

    __syncthreads();   // one barrier per tile (drains gl_lds vmcnt too)
  }

  // ---- epilogue: pair-sum l; fp16 unnormalized O^T partial + m,l ----
  float lt = l + __shfl_xor(l, 32, 64);
  f16* OPb = OP + ((size_t)(c * NB + b) * ND) * NS + qrow;
#pragma unroll
  for (int dt = 0; dt < 4; ++dt)
#pragma unroll
    for (int r = 0; r < 16; ++r) {
      int d = dt * 32 + (r & 3) + 8 * (r >> 2) + 4 * hi;
      OPb[(size_t)d * NS] = (f16)oacc[dt][r];
    }
  if (hi == 0) {
    Mp[(size_t)(c * NB + b) * NS + qrow] = m;
    Lp[(size_t)(c * NB + b) * NS + qrow] = lt;
  }
}

// ---------------------------------------------------------------------------
// Combine fp16 partials across chunks + transpose back to [b][q][d].
// Compile-time NC -> full unroll: independent 16B loads (ILP), coalesced.
// ---------------------------------------------------------------------------
template <int NC>
__global__ __launch_bounds__(256) void combine_kernel(
    const f16* __restrict__ OP, const float* __restrict__ Mp,
    const float* __restrict__ Lp, float* __restrict__ Out)
{
  __shared__ float wn[NC][64];
  __shared__ float LT[64][129];

  const int qtile = blockIdx.x, b = blockIdx.y;
  const int t = threadIdx.x;

  if (t < 64) {
    size_t qg = (size_t)qtile * 64 + t;
    float mv[NC], wloc[NC];
#pragma unroll
    for (int cc = 0; cc < NC; ++cc)
      mv[cc] = Mp[(size_t)(cc * NB + b) * NS + qg];
    float mx = mv[0];
#pragma unroll
    for (int cc = 1; cc < NC; ++cc) mx = fmaxf(mx, mv[cc]);
    float Lt = 0.f;
#pragma unroll
    for (int cc = 0; cc < NC; ++cc) {
      float w = exp2f(mv[cc] - mx);
      Lt += w * Lp[(size_t)(cc * NB + b) * NS + qg];
      wloc[cc] = w;
    }
    float inv = 1.0f / Lt;
#pragma unroll
    for (int cc = 0; cc < NC; ++cc) wn[cc][t] = wloc[cc] * inv;
  }
  __syncthreads();

  const int so = (t & 7) * 8;     // 8 q's per thread (16B along s)
  const int dl = t >> 3;          // 32 d's per pass
  const size_t sbase = (size_t)qtile * 64 + so;
#pragma unroll
  for (int dblk = 0; dblk < 4; ++dblk) {
    int d = dblk * 32 + dl;
    float a0 = 0, a1 = 0, a2 = 0, a3 = 0, a4 = 0, a5 = 0, a6 = 0, a7 = 0;
#pragma unroll
    for (int cc = 0; cc < NC; ++cc) {
      const f16* src = OP + ((size_t)(cc * NB + b) * ND + d) * NS + sbase;
      short8 v = *(const short8*)src;
      const float* w = &wn[cc][so];
      union { short s; f16 h; } u;
      u.s = v[0]; a0 += w[0] * (float)u.h;
      u.s = v[1]; a1 += w[1] * (float)u.h;
      u.s = v[2]; a2 += w[2] * (float)u.h;
      u.s = v[3]; a3 += w[3] * (float)u.h;
      u.s = v[4]; a4 += w[4] * (float)u.h;
      u.s = v[5]; a5 += w[5] * (float)u.h;
      u.s = v[6]; a6 += w[6] * (float)u.h;
      u.s = v[7]; a7 += w[7] * (float)u.h;
    }
    LT[so + 0][d] = a0; LT[so + 1][d] = a1;
    LT[so + 2][d] = a2; LT[so + 3][d] = a3;
    LT[so + 4][d] = a4; LT[so + 5][d] = a5;
    LT[so + 6][d] = a6; LT[so + 7][d] = a7;
  }
  __syncthreads();

  const int d2 = t & 127, qh = t >> 7;
  float* Ob = Out + ((size_t)b * NS + (size_t)qtile * 64) * ND;
#pragma unroll 8
  for (int pass = 0; pass < 32; ++pass) {
    int qq = pass * 2 + qh;
    Ob[(size_t)qq * ND + d2] = LT[qq][d2];
  }
}

extern "C" void kernel_launch(void* const* d_in, const int* in_sizes, int n_in,
                              void* d_out, int out_size, void* d_ws, size_t ws_size,
                              hipStream_t stream) {
  const float* x  = (const float*)d_in[0];
  const float* Wq = (const float*)d_in[1];
  const float* bq = (const float*)d_in[2];
  const float* Wk = (const float*)d_in[3];
  const float* bk = (const float*)d_in[4];
  const float* Wv = (const float*)d_in[5];
  const float* bv = (const float*)d_in[6];

  const size_t elems = (size_t)NB * NS * ND;
  char* base = (char*)d_ws;
  unsigned short* Qw  = (unsigned short*)base;
  unsigned short* Kw  = Qw + elems;
  unsigned short* Vtw = Kw + elems;
  char* region2 = base + 3 * elems * 2;            // 12 MB offset

  // split-KV factor: largest of {6,4,2,1} fitting ws (fp16 OP partials).
  int nchunk = 6;
  for (;;) {
    size_t need = 3 * elems * 2 +
                  (size_t)nchunk * (elems * 2 + 2 * (size_t)NB * NS * 4);
    if (need <= ws_size || nchunk == 1) break;
    nchunk = (nchunk == 6) ? 4 : nchunk >> 1;
  }

  // xb16/Wb16 alias the OP region (proj finishes before attn writes OP).
  unsigned short* xb16 = (unsigned short*)region2;
  unsigned short* Wb16 = xb16 + elems;
  f16* OPw = (f16*)region2;
  float* Mpw = (float*)(region2 + (size_t)nchunk * elems * 2);
  float* Lpw = Mpw + (size_t)nchunk * NB * NS;

  preconv_kernel<<<dim3(524), 512, 0, stream>>>(x, Wq, Wk, Wv, xb16, Wb16);

  proj_kernel<<<dim3(NS / 64, NB, 3), 256, 0, stream>>>(
      xb16, Wb16, bq, bk, bv, Qw, Kw, Vtw);

  attn_kernel<<<dim3(32 * NB * nchunk), 256, 0, stream>>>(
      Qw, Kw, Vtw, OPw, Mpw, Lpw, nchunk);

  dim3 cgrid(NS / 64, NB);
  switch (nchunk) {
    case 6: combine_kernel<6><<<cgrid, 256, 0, stream>>>(OPw, Mpw, Lpw, (float*)d_out); break;
    case 4: combine_kernel<4><<<cgrid, 256, 0, stream>>>(OPw, Mpw, Lpw, (float*)d_out); break;
    case 2: combine_kernel<2><<<cgrid, 256, 0, stream>>>(OPw, Mpw, Lpw, (float*)d_out); break;
    default: combine_kernel<1><<<cgrid, 256, 0, stream>>>(OPw, Mpw, Lpw, (float*)d_out); break;
  }
}